// Round 9
// baseline (756.253 us; speedup 1.0000x reference)
//
#include <hip/hip_runtime.h>
#include <hip/hip_bf16.h>
#include <stdint.h>

// Problem constants (fixed by the reference)
#define NN   50000
#define RR   50
#define BB   30
#define DIN  64
#define EE   1000000
#define E16MAX (EE + NN * 15)   // 1.75M padded records max
#define KTOT (BB*DIN + DIN)     // 1984
#define NBW  8                  // nodes per workgroup; 50000 = 6250*8 exactly
#define TROW8 1992              // t_tile row stride in shorts (16B-aligned)

typedef __attribute__((ext_vector_type(8)))  short short8;
typedef __attribute__((ext_vector_type(4)))  float floatx4;
typedef __attribute__((ext_vector_type(16))) float floatx16;

#define RFL(x) __builtin_amdgcn_readfirstlane(x)

// async 16B/lane global->LDS: dest = (wave-uniform) lds base + lane*16
__device__ __forceinline__ void async16(const void* g, void* l) {
    __builtin_amdgcn_global_load_lds(
        (const __attribute__((address_space(1))) unsigned int*)g,
        (__attribute__((address_space(3))) unsigned int*)l, 16, 0, 0);
}

// ---------------- preprocessing: counting sort of edges by dst ----------------

__global__ void k_hist(const int* __restrict__ dst, const int* __restrict__ et,
                       int* __restrict__ cnt, int* __restrict__ dcount) {
    int e = blockIdx.x * 256 + threadIdx.x;
    if (e < EE) {
        int d = dst[e], r = et[e];
        atomicAdd(&cnt[d * RR + r], 1);
        atomicAdd(&dcount[d], 1);
    }
}

// scan over degrees PADDED to multiple of 16
__global__ void k_scan1(const int* __restrict__ dcount, int* __restrict__ doff,
                        int* __restrict__ bsum) {
    __shared__ int sh[256];
    int t = threadIdx.x;
    int i = blockIdx.x * 256 + t;
    int v = (i < NN) ? ((dcount[i] + 15) & ~15) : 0;
    sh[t] = v;
    __syncthreads();
    for (int s = 1; s < 256; s <<= 1) {
        int add = (t >= s) ? sh[t - s] : 0;
        __syncthreads();
        sh[t] += add;
        __syncthreads();
    }
    int incl = sh[t];
    if (i < NN) doff[i] = incl - v;
    if (t == 255) bsum[blockIdx.x] = incl;
}

__global__ void k_scan2(int* __restrict__ bsum, int nbv) {
    __shared__ int sh[256];
    int t = threadIdx.x;
    int v = (t < nbv) ? bsum[t] : 0;
    sh[t] = v;
    __syncthreads();
    for (int s = 1; s < 256; s <<= 1) {
        int add = (t >= s) ? sh[t - s] : 0;
        __syncthreads();
        sh[t] += add;
        __syncthreads();
    }
    if (t < nbv) bsum[t] = sh[t] - v;
}

__global__ void k_scan3(int* __restrict__ doff, const int* __restrict__ bsum) {
    int i = blockIdx.x * 256 + threadIdx.x;
    if (i < NN) doff[i] += bsum[blockIdx.x];
}

__global__ void k_scatter(const int* __restrict__ src, const int* __restrict__ dst,
                          const int* __restrict__ et, const int* __restrict__ cnt,
                          const int* __restrict__ doff, int* __restrict__ cursor,
                          int4* __restrict__ epack) {
    int e = blockIdx.x * 256 + threadIdx.x;
    if (e < EE) {
        int d = dst[e], r = et[e], s = src[e];
        int p = doff[d] + atomicAdd(&cursor[d], 1);
        float a = 1.0f / (float)cnt[d * RR + r];
        epack[p] = make_int4(s, r, __float_as_int(a), 0);
        // padding records stay zero (memset): src=0, rel=0, alpha=0 -> contribute 0
    }
}

__global__ void k_cast_x(const float* __restrict__ x, __hip_bfloat16* __restrict__ h) {
    int i = blockIdx.x * 256 + threadIdx.x;
    if (i < NN * DIN) h[i] = __float2bfloat16(x[i]);
}

// all 3 layers' comp [R,30] fp32 -> bf16 padded [3][R][32] (zeros in 30,31)
__global__ void k_prep_cb3(const float* __restrict__ c0, const float* __restrict__ c1,
                           const float* __restrict__ c2, short* __restrict__ cb) {
    int idx = blockIdx.x * 256 + threadIdx.x;
    if (idx < 3 * RR * 32) {
        int l = idx / (RR * 32);
        int rem = idx - l * (RR * 32);
        int r = rem >> 5, i = rem & 31;
        const float* c = (l == 0) ? c0 : (l == 1) ? c1 : c2;
        float v = (i < BB) ? c[r * BB + i] : 0.f;
        __hip_bfloat16 hb = __float2bfloat16(v);
        cb[idx] = *reinterpret_cast<const short*>(&hb);
    }
}

// all 3 layers' transposed bf16 weights:
// rows [0,64): layer0; [64,128): layer1; [128,144): layer2 (dout=8, 16 padded rows)
__global__ void k_prep_w3(const float* __restrict__ b0, const float* __restrict__ r0,
                          const float* __restrict__ b1, const float* __restrict__ r1,
                          const float* __restrict__ b2, const float* __restrict__ r2,
                          short* __restrict__ wt) {
    int idx = blockIdx.x * 256 + threadIdx.x;
    if (idx >= 144 * KTOT) return;
    int row = idx / KTOT, k = idx - row * KTOT;
    const float* bs; const float* rt; int o, dout;
    if (row < 64)       { bs = b0; rt = r0; o = row;        dout = 64; }
    else if (row < 128) { bs = b1; rt = r1; o = row - 64;   dout = 64; }
    else                { bs = b2; rt = r2; o = row - 128;  dout = 8;  }
    float v = 0.f;
    if (o < dout)
        v = (k < BB * DIN) ? bs[k * dout + o] : rt[(k - BB * DIN) * dout + o];
    __hip_bfloat16 hb = __float2bfloat16(v);
    wt[idx] = *reinterpret_cast<const short*>(&hb);
}

// ---------------- fused per-layer kernel ----------------
// 1024 threads = 16 waves, NBW=8 nodes. Wave wv = (node j=wv>>1, feature-half h=wv&1).
// Phase 1: per 16-edge chunk (edges pre-padded to x16, alpha=0 pads):
//   records double-buffered in LDS via one lane<16 async16 (+exact vmcnt(1) wait:
//   the vmem queue holds ONLY record stages at that point);
//   x gathered per-lane into VGPRs (8 coalesced ushort loads, compiler-waited);
//   A = comp[rel][m]*alpha from LDS comp table; one mfma_f32_32x32x16_bf16 -> 16 AGPRs.
//   (16-AGPR acc keeps unified regs <=64 -> 8 waves/SIMD; R8's 32-AGPR version
//    dropped to 1 block/CU.)
// Phase 2: out = t(8xK) * Wt^T via 16x16x32 (rows 8..15 zero-padded);
//   DOUT=64: 4 col-tiles x 4 K-parts; DOUT=8: 16 K-parts; LDS reduction.
template <int DOUT, bool RELU>
__global__ __launch_bounds__(1024, 8)
void k_fused(const __hip_bfloat16* __restrict__ xin,
             const int4* __restrict__ epack,
             const int* __restrict__ doff16, const int* __restrict__ dcount,
             const short* __restrict__ cpb,     // [R][32] bf16 (this layer)
             const short* __restrict__ Wt,      // [DPAD][KTOT] bf16 (transposed)
             const float* __restrict__ bias,    // [DOUT]
             void* __restrict__ outp) {
    __shared__ __align__(16) char smem[43264];
    short* comp_lds = (short*)smem;                 // [0, 3200): 50 rows x 64B
    char*  recs     = smem + 3200;                  // [3200, 11392): 16 waves x 512B
    short* t_tile   = (short*)(smem + 11392);       // 8 x TROW8 shorts = 31872B

    const int tid  = threadIdx.x;
    const int lane = tid & 63;
    const int wv   = RFL(tid >> 6);          // 0..15
    const int node0 = blockIdx.x * NBW;
    const int j   = wv >> 1;
    const int h   = wv & 1;
    const int m31 = lane & 31;
    const int kh  = lane >> 5;

    // stage comp table (800 ints)
    for (int i = tid; i < 800; i += 1024)
        ((int*)comp_lds)[i] = ((const int*)cpb)[i];
    __syncthreads();

    // ---- phase 1 ----
    floatx16 acc = {0.f,0.f,0.f,0.f,0.f,0.f,0.f,0.f,0.f,0.f,0.f,0.f,0.f,0.f,0.f,0.f};
    const int n   = node0 + j;
    const int beg = RFL(doff16[n]);
    const int nch = (RFL(dcount[n]) + 15) >> 4;
    char* rs = recs + wv * 512;

    if (nch > 0) {
        if (lane < 16)
            async16((const char*)epack + ((size_t)beg + lane) * 16, rs);
        for (int c = 0; c < nch; ++c) {
            const char* cur = rs + (c & 1) * 256;
            char* nxt = rs + ((c + 1) & 1) * 256;
            if (c + 1 < nch) {
                if (lane < 16)
                    async16((const char*)epack + ((size_t)(beg + (c + 1) * 16) + lane) * 16, nxt);
                __builtin_amdgcn_s_waitcnt(0x0F71);   // vmcnt(1): cur landed, nxt in flight
            } else {
                __builtin_amdgcn_s_waitcnt(0x0F70);   // vmcnt(0): cur landed
            }
            unsigned short xv[8];
            float av[8];
#pragma unroll
            for (int t = 0; t < 8; ++t) {
                int4 rc = *(const int4*)(cur + (kh * 8 + t) * 16);
                // B element: x[src][h*32 + m31] raw bf16 (coalesced: 2 rows x 64B per load)
                xv[t] = *(const unsigned short*)((const char*)xin
                          + ((size_t)(unsigned)rc.x) * 128 + h * 64 + m31 * 2);
                // A element: comp[rel][m31] * alpha
                unsigned short cw = *(const unsigned short*)
                          ((const char*)comp_lds + rc.y * 64 + m31 * 2);
                float cf = __int_as_float(((int)cw) << 16);
                av[t] = cf * __int_as_float(rc.z);
            }
            short8 A, B;
#pragma unroll
            for (int t = 0; t < 8; ++t) {
                __hip_bfloat16 ab = __float2bfloat16(av[t]);
                A[t] = *reinterpret_cast<const short*>(&ab);
                B[t] = (short)xv[t];
            }
            acc = __builtin_amdgcn_mfma_f32_32x32x16_bf16(A, B, acc, 0, 0, 0);
        }
    }

    // epilogue: C/D (col=lane&31=feat, row=(reg&3)+8*(reg>>2)+4*kh=basis) -> t_tile
    {
        short* trow = t_tile + j * TROW8;
#pragma unroll
        for (int r = 0; r < 16; ++r) {
            const int b = (r & 3) + 8 * (r >> 2) + 4 * kh;
            if (b < BB) {
                __hip_bfloat16 hv = __float2bfloat16(acc[r]);
                trow[b * 64 + h * 32 + m31] = *reinterpret_cast<const short*>(&hv);
            }
        }
        // self/root term: raw bf16 copy (both kh halves write same value — benign)
        trow[BB * 64 + h * 32 + m31] = ((const short*)xin)[(size_t)n * 64 + h * 32 + m31];
    }
    __syncthreads();

    // ---- phase 2: MFMA 16x16x32, rows 8..15 zero-padded, K=1984 (62 steps) ----
    const int mm = lane & 15;
    const int qq = lane >> 4;
    int ct, kp, kk0, nst;
    if (DOUT == 64) {
        ct = wv & 3; kp = wv >> 2;
        kk0 = (kp <= 1) ? kp * 16 : (kp == 2 ? 32 : 47);
        nst = (kp <= 1) ? 16 : 15;
    } else {
        ct = 0; kp = wv;
        kk0 = (kp < 14) ? kp * 4 : 56 + (kp - 14) * 3;
        nst = (kp < 14) ? 4 : 3;
    }
    floatx4 p0 = {0.f, 0.f, 0.f, 0.f};
    {
        const short* arow = t_tile + mm * TROW8 + qq * 8;
        const short* wrow = Wt + (size_t)(ct * 16 + mm) * KTOT + qq * 8;
        for (int s = 0; s < nst; ++s) {
            const int kk = kk0 + s;
            short8 a = {0, 0, 0, 0, 0, 0, 0, 0};
            if (mm < NBW) a = *(const short8*)(arow + kk * 32);
            short8 w = *(const short8*)(wrow + kk * 32);
            p0 = __builtin_amdgcn_mfma_f32_16x16x32_bf16(a, w, p0, 0, 0, 0);
        }
    }
    __syncthreads();                 // t_tile reads done -> reuse smem for reduction
    float* red = (float*)smem;       // stride-5 float layout

    if (DOUT == 64) {
        if (kp > 0) {
            const int off = ((ct * 3 + (kp - 1)) * 64 + lane) * 5;
#pragma unroll
            for (int i = 0; i < 4; ++i) red[off + i] = p0[i];
        }
        __syncthreads();
        if (kp == 0) {
#pragma unroll
            for (int w = 0; w < 3; ++w) {
                const int off = ((ct * 3 + w) * 64 + lane) * 5;
#pragma unroll
                for (int i = 0; i < 4; ++i) p0[i] += red[off + i];
            }
            if (qq < 2) {            // node rows 0..7 only
                const int o = ct * 16 + mm;
                const float bi = bias[o];
#pragma unroll
                for (int r = 0; r < 4; ++r) {
                    const int nn = node0 + qq * 4 + r;
                    float v = p0[r] + bi;
                    if (RELU) {
                        v = fmaxf(v, 0.f);
                        reinterpret_cast<__hip_bfloat16*>(outp)[(size_t)nn * DOUT + o] =
                            __float2bfloat16(v);
                    } else {
                        reinterpret_cast<float*>(outp)[(size_t)nn * DOUT + o] = v;
                    }
                }
            }
        }
    } else {
        if (kp > 0) {
            const int off = ((kp - 1) * 64 + lane) * 5;
#pragma unroll
            for (int i = 0; i < 4; ++i) red[off + i] = p0[i];
        }
        __syncthreads();
        if (kp == 0) {
#pragma unroll
            for (int w = 0; w < 15; ++w) {
                const int off = (w * 64 + lane) * 5;
#pragma unroll
                for (int i = 0; i < 4; ++i) p0[i] += red[off + i];
            }
            if (mm < DOUT && qq < 2) {
                const float bi = bias[mm];
#pragma unroll
                for (int r = 0; r < 4; ++r) {
                    const int nn = node0 + qq * 4 + r;
                    reinterpret_cast<float*>(outp)[(size_t)nn * DOUT + mm] = p0[r] + bi;
                }
            }
        }
    }
}

// ---------------- log_softmax over C=8 ----------------
__global__ void k_lsm(const float* __restrict__ pre, float* __restrict__ out) {
    int n = blockIdx.x * 256 + threadIdx.x;
    if (n < NN) {
        float v[8];
        float mx = -1e30f;
#pragma unroll
        for (int c = 0; c < 8; ++c) { v[c] = pre[n * 8 + c]; mx = fmaxf(mx, v[c]); }
        float s = 0.f;
#pragma unroll
        for (int c = 0; c < 8; ++c) s += expf(v[c] - mx);
        float ls = logf(s);
#pragma unroll
        for (int c = 0; c < 8; ++c) out[n * 8 + c] = v[c] - mx - ls;
    }
}

// ---------------- launch ----------------
extern "C" void kernel_launch(void* const* d_in, const int* in_sizes, int n_in,
                              void* d_out, int out_size, void* d_ws, size_t ws_size,
                              hipStream_t stream) {
    const float* x     = (const float*)d_in[0];
    const int*   eidx  = (const int*)d_in[1];
    const int*   etype = (const int*)d_in[2];
    const float* bases0 = (const float*)d_in[3];
    const float* comp0  = (const float*)d_in[4];
    const float* root0  = (const float*)d_in[5];
    const float* bias0  = (const float*)d_in[6];
    const float* bases1 = (const float*)d_in[7];
    const float* comp1  = (const float*)d_in[8];
    const float* root1  = (const float*)d_in[9];
    const float* bias1  = (const float*)d_in[10];
    const float* bases2 = (const float*)d_in[11];
    const float* comp2  = (const float*)d_in[12];
    const float* root2  = (const float*)d_in[13];
    const float* bias2  = (const float*)d_in[14];
    const int* srcp = eidx;
    const int* dstp = eidx + EE;

    char* p = (char*)d_ws;
    auto carve = [&](size_t bytes) -> char* {
        char* r = p;
        p += (bytes + 255) & ~(size_t)255;
        return r;
    };
    int*  cnt    = (int*)carve((size_t)NN * RR * sizeof(int));   // 10 MB
    int*  dcount = (int*)carve((size_t)NN * sizeof(int));
    int*  cursor = (int*)carve((size_t)NN * sizeof(int));
    int*  doff   = (int*)carve((size_t)NN * sizeof(int));
    int*  bsum   = (int*)carve(256 * sizeof(int));
    int4* epack  = (int4*)carve((size_t)E16MAX * sizeof(int4) + 512);  // 28 MB padded records
    __hip_bfloat16* h0 = (__hip_bfloat16*)carve((size_t)NN * DIN * 2);
    __hip_bfloat16* h1 = (__hip_bfloat16*)carve((size_t)NN * DIN * 2);
    __hip_bfloat16* h2 = (__hip_bfloat16*)carve((size_t)NN * DIN * 2);
    float* pre = (float*)carve((size_t)NN * 8 * sizeof(float));
    short* wtA = (short*)carve((size_t)144 * KTOT * sizeof(short));  // 3 layers stacked
    short* cbA = (short*)carve((size_t)3 * RR * 32 * sizeof(short)); // bf16 comp tables

    // zero: cnt/dcount/cursor (adjacent) and the padded epack (pads must be 0)
    hipMemsetAsync(cnt, 0, (size_t)NN * (RR + 2) * sizeof(int) + 512, stream);
    hipMemsetAsync(epack, 0, (size_t)E16MAX * sizeof(int4), stream);

    const int EB = (EE + 255) / 256;   // 3907
    const int NB = (NN + 255) / 256;   // 196
    k_hist<<<EB, 256, 0, stream>>>(dstp, etype, cnt, dcount);
    k_scan1<<<NB, 256, 0, stream>>>(dcount, doff, bsum);
    k_scan2<<<1, 256, 0, stream>>>(bsum, NB);
    k_scan3<<<NB, 256, 0, stream>>>(doff, bsum);
    k_scatter<<<EB, 256, 0, stream>>>(srcp, dstp, etype, cnt, doff, cursor, epack);
    k_cast_x<<<(NN * DIN + 255) / 256, 256, 0, stream>>>(x, h0);
    k_prep_cb3<<<(3 * RR * 32 + 255) / 256, 256, 0, stream>>>(comp0, comp1, comp2, cbA);
    k_prep_w3<<<(144 * KTOT + 255) / 256, 256, 0, stream>>>(bases0, root0, bases1, root1,
                                                            bases2, root2, wtA);

    short* wt0 = wtA;
    short* wt1 = wtA + (size_t)64 * KTOT;
    short* wt2 = wtA + (size_t)128 * KTOT;
    short* cb0 = cbA;
    short* cb1 = cbA + RR * 32;
    short* cb2 = cbA + 2 * RR * 32;

    const int NF = NN / NBW;   // 6250 (exact)
    k_fused<64, true ><<<NF, 1024, 0, stream>>>(h0, epack, doff, dcount, cb0, wt0, bias0, (void*)h1);
    k_fused<64, true ><<<NF, 1024, 0, stream>>>(h1, epack, doff, dcount, cb1, wt1, bias1, (void*)h2);
    k_fused<8,  false><<<NF, 1024, 0, stream>>>(h2, epack, doff, dcount, cb2, wt2, bias2, (void*)pre);
    k_lsm<<<NB, 256, 0, stream>>>(pre, (float*)d_out);
}